// Round 11
// baseline (221.065 us; speedup 1.0000x reference)
//
#include <hip/hip_runtime.h>
#include <hip/hip_bf16.h>

#define N_NODES 50000
#define N_EDGES 800000
#define BM 64
#define NBUCK 196            // buckets of 256 nodes: d >> 8
#define CAP 8192             // csr per-bucket capacity (real ~4096 + pad <=1792)
#define CHUNK 2048           // edges per bucket-chunk block
#define NCHUNK ((N_EDGES + CHUNK - 1) / CHUNK)             // 391
#define SUBCAP 32            // per-(bucket,chunk) fixed slots (mean 10.4, 6.7 sigma)
#define DCAP 5120            // dense LDS staging pairs (bucket mean 4081, 16 sigma)
#define SWZ_BLOCKS 192                                     // 49152 halves
#define SWZ_G 32768          // W_gat offset in swz
#define GBLK ((N_NODES + BM - 1) / BM)                     // 782
#define SXP 136              // sx row pitch f16 (272B: 16B-aligned, 2-way banks)
#define SEP 72               // se row pitch f16 (144B: 16B-aligned, 2-way banks)
#define SMEM_BYTES (64 * SXP * 2 + 64 * 132 * 4)           // 51200
#define NQ 4                 // channel quarters (32 ch = 1 head each)
#define NBPQ ((N_NODES + 3) / 4)                           // 12500 node-blocks/quarter
#define HPLANE 800000        // uints per h plane (50000 rows x 16 uints)

typedef _Float16 half4v __attribute__((ext_vector_type(4)));
typedef _Float16 half8 __attribute__((ext_vector_type(8)));
typedef float    float4v __attribute__((ext_vector_type(4)));

__device__ __forceinline__ float elu_f(float v) {
    return (v > 0.f) ? v : (__expf(v) - 1.f);
}

// pack two fp32 -> packed bf16x2 (RNE)
__device__ __forceinline__ unsigned f2bf2(float a, float b) {
    unsigned ua = __float_as_uint(a), ub = __float_as_uint(b);
    ua = (ua + 0x7FFFu + ((ua >> 16) & 1u)) >> 16;
    ub = (ub + 0x7FFFu + ((ub >> 16) & 1u)) >> 16;
    return ua | (ub << 16);
}
__device__ __forceinline__ float2 bf2f2(unsigned u) {
    float2 f;
    f.x = __uint_as_float(u << 16);
    f.y = __uint_as_float(u & 0xFFFF0000u);
    return f;
}

// ---------------- L1: weight swizzle [0,192) ∥ bucket-fixed [192,583) ----
__global__ __launch_bounds__(256) void k_pre_bucket(const void* __restrict__ e_raw,
        const float* __restrict__ We, const float* __restrict__ Wd,
        const float* __restrict__ Wo, const float* __restrict__ Wg,
        _Float16* __restrict__ swz, uint2* __restrict__ ebuck2,
        int* __restrict__ cnt) {
    const int b = blockIdx.x;
    const int tid = threadIdx.x;
    if (b >= SWZ_BLOCKS) {
        // ---- bucket chunk c ----
        __shared__ int lh[256];
        __shared__ int isl;
        const int c = b - SWZ_BLOCKS;
        const int base = c * CHUNK;
        const long long* e64 = (const long long*)e_raw;
        const int* e32 = (const int*)e_raw;
        if (tid == 0) {
            const unsigned* er = (const unsigned*)e_raw;
            int nz = 0;
            for (int j = 0; j < 64; j++) nz |= (er[2 * (base + j) + 1] != 0u);
            isl = nz ? 0 : 1;
        }
        lh[tid] = 0;
        __syncthreads();
        const int is64 = isl;
#pragma unroll 4
        for (int j = 0; j < CHUNK / 256; j++) {
            int e = base + j * 256 + tid;
            if (e < N_EDGES) {
                int sN, d;
                if (is64) { sN = (int)e64[e]; d = (int)e64[N_EDGES + e]; }
                else      { sN = e32[e];      d = e32[N_EDGES + e]; }
                int bb = d >> 8;
                int pos = atomicAdd(&lh[bb], 1);
                if (pos < SUBCAP) {   // 6.7-sigma guard
                    uint2 pr; pr.x = (unsigned)sN; pr.y = (unsigned)d;
                    ebuck2[((size_t)bb * NCHUNK + c) * SUBCAP + pos] = pr;
                }
            }
        }
        __syncthreads();
        int v = lh[tid]; if (v > SUBCAP) v = SUBCAP;
        cnt[c * 256 + tid] = v;
        return;
    }
    // ---- weight swizzle ----
    int t = b * 256 + tid;
    const float* W; int base, N;
    if (t < 8192)       { W = We; base = 0;     N = 64;  }
    else if (t < 16384) { W = Wd; base = 8192;  N = 128; }
    else if (t < 32768) { W = Wo; base = 16384; N = 128; }
    else                { W = Wg; base = SWZ_G; N = 128; }
    int loc = t - base;
    int nnt = N >> 4;
    int frag = loc >> 9, r = loc & 511, lane = r >> 3, j = r & 7;
    int kc = frag / nnt, nt = frag - kc * nnt;
    int k = kc * 32 + ((lane >> 4) << 3) + j;
    int n = nt * 16 + (lane & 15);
    swz[t] = (_Float16)W[k * N + n];
}

// ---------------- L2: bfill' blocks [0,196) ∥ gat_lin blocks [196,978) ---
__global__ __launch_bounds__(256) void k_lin_bfill(
        const float* __restrict__ x, const _Float16* __restrict__ swz,
        const float* __restrict__ att_s, const float* __restrict__ att_d,
        unsigned* __restrict__ h_bf, float* __restrict__ a_src,
        float* __restrict__ a_dst,
        const uint2* __restrict__ ebuck2, const int* __restrict__ cnt,
        int2* __restrict__ nodeoff, int* __restrict__ csr_src) {
    __shared__ __align__(16) char smem[SMEM_BYTES];
    const int tid = threadIdx.x;

    if (blockIdx.x < NBUCK) {
        // ---- bfill' for bucket bkt ----
        uint2* dense = (uint2*)smem;                     // DCAP*8 = 40960
        int*   coff  = (int*)(smem + 40960);             // 392*4  = 1568
        int*   sc    = (int*)(smem + 42528);             // 1024
        int*   lh    = (int*)(smem + 43552);             // 1024
        int*   lexc  = (int*)(smem + 44576);             // 1024
        int*   lcur  = (int*)(smem + 45600);             // 1024
        const int bkt = blockIdx.x;
        const int lo = bkt * CAP;
        const int n0 = bkt << 8;

        // A: chunk-count scan (391 values, two 256-wide rounds)
        int v0 = cnt[tid * 256 + bkt];                   // chunks 0..255
        sc[tid] = v0;
        __syncthreads();
        for (int o = 1; o < 256; o <<= 1) {
            int u = (tid >= o) ? sc[tid - o] : 0;
            __syncthreads();
            sc[tid] += u;
            __syncthreads();
        }
        coff[tid] = sc[tid] - v0;
        int total0 = sc[255];
        __syncthreads();
        int c2 = tid + 256;
        int v1 = (c2 < NCHUNK) ? cnt[c2 * 256 + bkt] : 0;
        sc[tid] = v1;
        __syncthreads();
        for (int o = 1; o < 256; o <<= 1) {
            int u = (tid >= o) ? sc[tid - o] : 0;
            __syncthreads();
            sc[tid] += u;
            __syncthreads();
        }
        if (c2 < NCHUNK) coff[c2] = total0 + sc[tid] - v1;
        int cntb = total0 + sc[255];
        if (cntb > DCAP) cntb = DCAP;
        if (tid == 0) coff[NCHUNK] = cntb;
        __syncthreads();

        // B: compact to dense LDS (8 threads per chunk, 32 chunks in flight)
        {
            int cg = tid >> 3, j = tid & 7;
            for (int c = cg; c < NCHUNK; c += 32) {
                int off = coff[c];
                int n = coff[c + 1] - off;
                const uint2* src = &ebuck2[((size_t)bkt * NCHUNK + c) * SUBCAP];
                for (int e = j; e < n; e += 8)
                    if (off + e < DCAP) dense[off + e] = src[e];
            }
        }
        __syncthreads();

        // C: node histogram from LDS
        lh[tid] = 0;
        lcur[tid] = 0;
        __syncthreads();
        for (int i = tid; i < cntb; i += 256)
            atomicAdd(&lh[dense[i].y & 255], 1);
        __syncthreads();

        // D: padded (x8) exclusive scan -> nodeoff
        int v = lh[tid];
        int p = (v + 7) & ~7;
        lexc[tid] = p;
        __syncthreads();
        for (int o = 1; o < 256; o <<= 1) {
            int u = (tid >= o) ? lexc[tid - o] : 0;
            __syncthreads();
            lexc[tid] += u;
            __syncthreads();
        }
        {
            int s = lexc[tid] - p;   // exclusive padded start
            lexc[tid] = s;
            int node = n0 + tid;
            if (node < N_NODES) {
                int2 no;
                no.x = lo + s;
                int maxlen = CAP - s; if (maxlen < 0) maxlen = 0;
                no.y = p <= maxlen ? p : (maxlen & ~7);
                nodeoff[node] = no;
            }
        }
        __syncthreads();

        // E: scatter + F: sentinel pad
        for (int i = tid; i < cntb; i += 256) {
            uint2 pr = dense[i];
            int li = (int)(pr.y & 255);
            int pos = atomicAdd(&lcur[li], 1);
            int dst = lexc[li] + pos;
            if (dst < CAP) csr_src[lo + dst] = (int)pr.x;
        }
        {
            int base2 = lexc[tid];
            for (int j = v; j < p && base2 + j < CAP; j++)
                csr_src[lo + base2 + j] = -1;
        }
        return;
    }

    // ---- gat_lin body: h(bf16) = x @ W_gat via MFMA; att head dots ----
    _Float16* sx = (_Float16*)smem;                    // 64 x SXP f16
    float*    sh = (float*)(smem + 64 * SXP * 2);      // 64 x 132 f32
    const int m0 = (blockIdx.x - NBUCK) * 64;

#pragma unroll
    for (int i = 0; i < 8; i++) {
        int idx = tid + i * 256;        // 2048 float4 slots (64 x 32)
        int r = idx >> 5, c4 = idx & 31;
        int row = m0 + r; if (row >= N_NODES) row = N_NODES - 1;
        float4 v = ((const float4*)(x + (size_t)row * 128))[c4];
        half4v h;
        h[0] = (_Float16)v.x; h[1] = (_Float16)v.y;
        h[2] = (_Float16)v.z; h[3] = (_Float16)v.w;
        *(half4v*)&sx[r * SXP + c4 * 4] = h;
    }
    __syncthreads();

    const int wave = tid >> 6, lane = tid & 63;
    const int lm = lane & 15, lq = lane >> 4;
    const int wrow = wave * 16;

    {
        float4v acc[8];
#pragma unroll
        for (int nt = 0; nt < 8; nt++) acc[nt] = (float4v){0.f, 0.f, 0.f, 0.f};
#pragma unroll
        for (int kc = 0; kc < 4; kc++) {
            half8 a = *(const half8*)&sx[(wrow + lm) * SXP + kc * 32 + lq * 8];
#pragma unroll
            for (int nt = 0; nt < 8; nt++) {
                half8 b = *(const half8*)&swz[SWZ_G + (kc * 8 + nt) * 512 + lane * 8];
                acc[nt] = __builtin_amdgcn_mfma_f32_16x16x32_f16(a, b, acc[nt], 0, 0, 0);
            }
        }
        // C/D layout: col = nt*16 + lm, row = lq*4 + r
#pragma unroll
        for (int nt = 0; nt < 8; nt++)
#pragma unroll
            for (int r = 0; r < 4; r++)
                sh[(wrow + lq * 4 + r) * 132 + nt * 16 + lm] = acc[nt][r];
    }
    __syncthreads();

    // epilogue: pack bf16 h (plane-major quarters) + attention dots
    const int c0 = (tid & 31) * 4;
    const int r0 = (tid >> 5) * 8;
    float4 as4 = *(const float4*)&att_s[c0];
    float4 ad4 = *(const float4*)&att_d[c0];
    const int head = c0 >> 5;
    const int pl = c0 >> 5;              // channel quarter (= head)
    const int ci = (c0 & 31) >> 1;       // uint offset within 16-uint row

#pragma unroll
    for (int r = 0; r < 8; r++) {
        int row = m0 + r0 + r;
        bool ok = row < N_NODES;
        float4 hv = *(const float4*)&sh[(r0 + r) * 132 + c0];
        if (ok) {
            uint2 p;
            p.x = f2bf2(hv.x, hv.y);
            p.y = f2bf2(hv.z, hv.w);
            *(uint2*)&h_bf[(size_t)pl * HPLANE + (size_t)row * 16 + ci] = p;
        }
        float vs = hv.x * as4.x + hv.y * as4.y + hv.z * as4.z + hv.w * as4.w;
        float vd = hv.x * ad4.x + hv.y * ad4.y + hv.z * ad4.z + hv.w * ad4.w;
#pragma unroll
        for (int o = 4; o >= 1; o >>= 1) {
            vs += __shfl_down(vs, o, 8);
            vd += __shfl_down(vd, o, 8);
        }
        if (ok && (tid & 7) == 0) {
            a_src[row * 4 + head] = vs;
            a_dst[row * 4 + head] = vd;
        }
    }
}

// ---------------- K3: channel-quartered CSR gather -----------------------
// Quarter q (= head q) per block; h plane q (3.2 MB) fits one XCD L2.
// Wave = 1 node: 16 edge-groups x 2 edges x 4 octets (32 edges/iter).
__global__ __launch_bounds__(256) void k_gather(const int2* __restrict__ nodeoff,
        const int* __restrict__ csr_src, const float* __restrict__ a_src,
        const float* __restrict__ a_dst, const unsigned* __restrict__ h_bf,
        const float* __restrict__ b_gat, _Float16* __restrict__ x1) {
    const int q  = blockIdx.x / NBPQ;        // quarter 0..3 (q-major dispatch)
    const int nb = blockIdx.x - q * NBPQ;
    int d = nb * 4 + (threadIdx.x >> 6);
    if (d >= N_NODES) return;
    const int lane = threadIdx.x & 63;
    const int eg  = lane >> 2;               // edge group 0..15 (2 edges each)
    const int lc2 = lane & 3;                // octet within quarter
    const uint4* hb = (const uint4*)(h_bf + (size_t)q * HPLANE);  // plane q
    int2 nd = nodeoff[d];
    const int lo = nd.x, hi = nd.x + nd.y;   // padded len (x8)

    const float adh = a_dst[(unsigned)(d * 4 + q)];

    float den = 0.f;
    float c0 = 0.f, c1 = 0.f, c2 = 0.f, c3 = 0.f;
    float c4 = 0.f, c5 = 0.f, c6 = 0.f, c7 = 0.f;

    if (eg == 0) {   // self-loop on group 0 (4 lanes cover the 32 ch)
        float t = a_src[(unsigned)(d * 4 + q)] + adh;
        t = t > 0.f ? t : 0.2f * t;
        float es = __expf(t);
        den = es;
        uint4 u = hb[(unsigned)d * 4 + lc2];
        float2 p0 = bf2f2(u.x), p1 = bf2f2(u.y), p2 = bf2f2(u.z), p3 = bf2f2(u.w);
        c0 = p0.x * es; c1 = p0.y * es; c2 = p1.x * es; c3 = p1.y * es;
        c4 = p2.x * es; c5 = p2.y * es; c6 = p3.x * es; c7 = p3.y * es;
    }

    for (int base = lo; base < hi; base += 32) {
        int i0 = base + eg * 2;
        int2 sv = *(const int2*)&csr_src[i0];   // safe: region padded
        bool ok = i0 < hi;                      // slots >= hi masked as sentinel
        int sA = ok ? sv.x : -1;
        int sB = ok ? sv.y : -1;
        unsigned gA = (unsigned)(sA < 0 ? d : sA);
        unsigned gB = (unsigned)(sB < 0 ? d : sB);
        uint4 uA = hb[gA * 4 + lc2];
        uint4 uB = hb[gB * 4 + lc2];
        float aA = a_src[gA * 4 + q];
        float aB = a_src[gB * 4 + q];

        float tA = aA + adh; tA = tA > 0.f ? tA : 0.2f * tA;
        float tB = aB + adh; tB = tB > 0.f ? tB : 0.2f * tB;
        float eA = sA < 0 ? 0.f : __expf(tA);
        float eB = sB < 0 ? 0.f : __expf(tB);
        den += eA + eB;

        float2 p0, p1, p2, p3;
        p0 = bf2f2(uA.x); p1 = bf2f2(uA.y); p2 = bf2f2(uA.z); p3 = bf2f2(uA.w);
        c0 = fmaf(p0.x, eA, c0); c1 = fmaf(p0.y, eA, c1);
        c2 = fmaf(p1.x, eA, c2); c3 = fmaf(p1.y, eA, c3);
        c4 = fmaf(p2.x, eA, c4); c5 = fmaf(p2.y, eA, c5);
        c6 = fmaf(p3.x, eA, c6); c7 = fmaf(p3.y, eA, c7);
        p0 = bf2f2(uB.x); p1 = bf2f2(uB.y); p2 = bf2f2(uB.z); p3 = bf2f2(uB.w);
        c0 = fmaf(p0.x, eB, c0); c1 = fmaf(p0.y, eB, c1);
        c2 = fmaf(p1.x, eB, c2); c3 = fmaf(p1.y, eB, c3);
        c4 = fmaf(p2.x, eB, c4); c5 = fmaf(p2.y, eB, c5);
        c6 = fmaf(p3.x, eB, c6); c7 = fmaf(p3.y, eB, c7);
    }

    // reduce across the 16 edge-groups (lanes with same lc2)
#pragma unroll
    for (int o = 4; o <= 32; o <<= 1) {
        den += __shfl_xor(den, o);
        c0 += __shfl_xor(c0, o); c1 += __shfl_xor(c1, o);
        c2 += __shfl_xor(c2, o); c3 += __shfl_xor(c3, o);
        c4 += __shfl_xor(c4, o); c5 += __shfl_xor(c5, o);
        c6 += __shfl_xor(c6, o); c7 += __shfl_xor(c7, o);
    }

    if (lane < 4) {
        float inv = 1.f / (den + 1e-16f);
        float4 bg0 = ((const float4*)b_gat)[q * 8 + lc2 * 2];
        float4 bg1 = ((const float4*)b_gat)[q * 8 + lc2 * 2 + 1];
        half8 hv;
        hv[0] = (_Float16)elu_f(fmaf(c0, inv, bg0.x));
        hv[1] = (_Float16)elu_f(fmaf(c1, inv, bg0.y));
        hv[2] = (_Float16)elu_f(fmaf(c2, inv, bg0.z));
        hv[3] = (_Float16)elu_f(fmaf(c3, inv, bg0.w));
        hv[4] = (_Float16)elu_f(fmaf(c4, inv, bg1.x));
        hv[5] = (_Float16)elu_f(fmaf(c5, inv, bg1.y));
        hv[6] = (_Float16)elu_f(fmaf(c6, inv, bg1.z));
        hv[7] = (_Float16)elu_f(fmaf(c7, inv, bg1.w));
        *(half8*)&x1[(size_t)d * 128 + q * 32 + lc2 * 8] = hv;
    }
}

// ---------------- K4: fused MLP via MFMA f16 (f16 input, padded LDS) -----
__global__ __launch_bounds__(256) void k_mlp(const _Float16* __restrict__ x1,
        const _Float16* __restrict__ swz, const float* __restrict__ b_enc,
        const float* __restrict__ b_dec, const float* __restrict__ b_out,
        float* __restrict__ out) {
    __shared__ _Float16 sx[64 * SXP];          // 17 KB
    __shared__ _Float16 se[4 * 16 * SEP];      // 9 KB
    const int tid = threadIdx.x;
    const int m0 = blockIdx.x * 64;

    // stage X1 (already elu(agg+b_gat), f16) -> padded LDS, pure copies
#pragma unroll
    for (int i = 0; i < 4; i++) {
        int idx = tid + i * 256;        // 1024 uint4 slots (64 rows x 16)
        int r = idx >> 4, c = idx & 15;
        int row = m0 + r; if (row >= N_NODES) row = N_NODES - 1;
        uint4 v = ((const uint4*)(x1 + (size_t)row * 128))[c];
        *(uint4*)&sx[r * SXP + c * 8] = v;
    }
    __syncthreads();

    const int wave = tid >> 6, lane = tid & 63;
    const int lm = lane & 15, lq = lane >> 4;
    const int wrow = wave * 16;
    _Float16* eslab = &se[wave * 16 * SEP];

    // L1: E = X1 @ W_enc + b_enc
    {
        float4v acc[4];
#pragma unroll
        for (int nt = 0; nt < 4; nt++) acc[nt] = (float4v){0.f, 0.f, 0.f, 0.f};
#pragma unroll
        for (int kc = 0; kc < 4; kc++) {
            half8 a = *(const half8*)&sx[(wrow + lm) * SXP + kc * 32 + lq * 8];
#pragma unroll
            for (int nt = 0; nt < 4; nt++) {
                half8 b = *(const half8*)&swz[(kc * 4 + nt) * 512 + lane * 8];
                acc[nt] = __builtin_amdgcn_mfma_f32_16x16x32_f16(a, b, acc[nt], 0, 0, 0);
            }
        }
#pragma unroll
        for (int nt = 0; nt < 4; nt++) {
            float be = b_enc[nt * 16 + lm];
#pragma unroll
            for (int r = 0; r < 4; r++)
                eslab[(lq * 4 + r) * SEP + nt * 16 + lm] = (_Float16)(acc[nt][r] + be);
        }
    }

    // L2: X2 = elu(E @ W_dec + b_dec) -> sx slab
    {
        float4v acc[8];
#pragma unroll
        for (int nt = 0; nt < 8; nt++) acc[nt] = (float4v){0.f, 0.f, 0.f, 0.f};
#pragma unroll
        for (int kc = 0; kc < 2; kc++) {
            half8 a = *(const half8*)&eslab[lm * SEP + kc * 32 + lq * 8];
#pragma unroll
            for (int nt = 0; nt < 8; nt++) {
                half8 b = *(const half8*)&swz[8192 + (kc * 8 + nt) * 512 + lane * 8];
                acc[nt] = __builtin_amdgcn_mfma_f32_16x16x32_f16(a, b, acc[nt], 0, 0, 0);
            }
        }
#pragma unroll
        for (int nt = 0; nt < 8; nt++) {
            float bd = b_dec[nt * 16 + lm];
#pragma unroll
            for (int r = 0; r < 4; r++)
                sx[(wrow + lq * 4 + r) * SXP + nt * 16 + lm] =
                    (_Float16)elu_f(acc[nt][r] + bd);
        }
    }

    // L3: OUT = X2 @ W_out + b_out
    {
        float4v acc[8];
#pragma unroll
        for (int nt = 0; nt < 8; nt++) acc[nt] = (float4v){0.f, 0.f, 0.f, 0.f};
#pragma unroll
        for (int kc = 0; kc < 4; kc++) {
            half8 a = *(const half8*)&sx[(wrow + lm) * SXP + kc * 32 + lq * 8];
#pragma unroll
            for (int nt = 0; nt < 8; nt++) {
                half8 b = *(const half8*)&swz[16384 + (kc * 8 + nt) * 512 + lane * 8];
                acc[nt] = __builtin_amdgcn_mfma_f32_16x16x32_f16(a, b, acc[nt], 0, 0, 0);
            }
        }
#pragma unroll
        for (int nt = 0; nt < 8; nt++) {
            float bo = b_out[nt * 16 + lm];
#pragma unroll
            for (int r = 0; r < 4; r++) {
                int row = m0 + wrow + lq * 4 + r;
                if (row < N_NODES)
                    out[(size_t)row * 128 + nt * 16 + lm] = acc[nt][r] + bo;
            }
        }
    }
}

extern "C" void kernel_launch(void* const* d_in, const int* in_sizes, int n_in,
                              void* d_out, int out_size, void* d_ws, size_t ws_size,
                              hipStream_t stream) {
    const float* x       = (const float*)d_in[0];
    const void*  e_raw   = d_in[1];
    const float* W_gat   = (const float*)d_in[2];
    const float* b_gat   = (const float*)d_in[3];
    const float* att_src = (const float*)d_in[4];
    const float* att_dst = (const float*)d_in[5];
    const float* W_enc   = (const float*)d_in[6];
    const float* b_enc   = (const float*)d_in[7];
    const float* W_dec   = (const float*)d_in[8];
    const float* b_dec   = (const float*)d_in[9];
    const float* W_out   = (const float*)d_in[10];
    const float* b_out   = (const float*)d_in[11];
    float* out = (float*)d_out;

    float* ws      = (float*)d_ws;
    unsigned* h_bf = (unsigned*)ws;            // 4 planes x 800,000 u = 12.8 MB
    float* a_src   = ws + 6400000;             // 200,000 f
    float* a_dst   = a_src + 200000;           // 200,000 f
    float* agg     = a_dst + 200000;           // 6.4M-float region, reused:
    uint2* ebuck2  = (uint2*)agg;              //   196*391*32*8B = 19.6 MB
    _Float16* x1   = (_Float16*)agg;           //   12.8 MB (after bfill' done)
    int*   csr_src = (int*)(agg + 6400000);    // 196*8192 = 1,605,632 i
    int*   cnt     = csr_src + NBUCK * CAP;    // 391*256 = 100,096 i
    int2*  nodeoff = (int2*)(cnt + NCHUNK * 256);     // 50,000 int2
    _Float16* swz  = (_Float16*)(((uintptr_t)(nodeoff + 50000) + 15) & ~(uintptr_t)15);

    k_pre_bucket<<<SWZ_BLOCKS + NCHUNK, 256, 0, stream>>>(
        e_raw, W_enc, W_dec, W_out, W_gat, swz, ebuck2, cnt);

    k_lin_bfill<<<NBUCK + GBLK, 256, 0, stream>>>(
        x, swz, att_src, att_dst, h_bf, a_src, a_dst,
        ebuck2, cnt, nodeoff, csr_src);

    k_gather<<<NQ * NBPQ, 256, 0, stream>>>(
        nodeoff, csr_src, a_src, a_dst, h_bf, b_gat, x1);

    k_mlp<<<GBLK, 256, 0, stream>>>(x1, swz, b_enc, b_dec, b_out, out);
}

// Round 12
// 175.078 us; speedup vs baseline: 1.2627x; 1.2627x over previous
//
#include <hip/hip_runtime.h>
#include <hip/hip_bf16.h>

#define N_NODES 50000
#define N_EDGES 800000
#define BM 64
#define NBUCK 196            // buckets of 256 nodes: d >> 8
#define CAP 8192             // csr per-bucket capacity (real ~4096 + pad <=1792)
#define CHUNK 2048           // edges per bucket-chunk block
#define NCHUNK ((N_EDGES + CHUNK - 1) / CHUNK)             // 391
#define SUBCAP 32            // per-(bucket,chunk) fixed slots (mean 10.4, 6.7 sigma)
#define DCAP 5120            // dense LDS staging pairs (bucket mean 4081, 16 sigma)
#define SWZ_BLOCKS 192                                     // 49152 halves
#define SWZ_G 32768          // W_gat offset in swz
#define GBLK ((N_NODES + BM - 1) / BM)                     // 782
#define SXP 136              // sx row pitch f16 (272B: 16B-aligned, 2-way banks)
#define SEP 72               // se row pitch f16 (144B: 16B-aligned, 2-way banks)
#define SMEM_BYTES (64 * SXP * 2 + 64 * 132 * 4)           // 51200

typedef _Float16 half4v __attribute__((ext_vector_type(4)));
typedef _Float16 half8 __attribute__((ext_vector_type(8)));
typedef float    float4v __attribute__((ext_vector_type(4)));

__device__ __forceinline__ float elu_f(float v) {
    return (v > 0.f) ? v : (__expf(v) - 1.f);
}

// pack two fp32 -> packed bf16x2 (RNE)
__device__ __forceinline__ unsigned f2bf2(float a, float b) {
    unsigned ua = __float_as_uint(a), ub = __float_as_uint(b);
    ua = (ua + 0x7FFFu + ((ua >> 16) & 1u)) >> 16;
    ub = (ub + 0x7FFFu + ((ub >> 16) & 1u)) >> 16;
    return ua | (ub << 16);
}
__device__ __forceinline__ float2 bf2f2(unsigned u) {
    float2 f;
    f.x = __uint_as_float(u << 16);
    f.y = __uint_as_float(u & 0xFFFF0000u);
    return f;
}

// ---------------- L1: weight swizzle [0,192) ∥ bucket-fixed [192,583) ----
__global__ __launch_bounds__(256) void k_pre_bucket(const void* __restrict__ e_raw,
        const float* __restrict__ We, const float* __restrict__ Wd,
        const float* __restrict__ Wo, const float* __restrict__ Wg,
        _Float16* __restrict__ swz, uint2* __restrict__ ebuck2,
        int* __restrict__ cnt) {
    const int b = blockIdx.x;
    const int tid = threadIdx.x;
    if (b >= SWZ_BLOCKS) {
        // ---- bucket chunk c ----
        __shared__ int lh[256];
        __shared__ int isl;
        const int c = b - SWZ_BLOCKS;
        const int base = c * CHUNK;
        const long long* e64 = (const long long*)e_raw;
        const int* e32 = (const int*)e_raw;
        if (tid == 0) {
            const unsigned* er = (const unsigned*)e_raw;
            int nz = 0;
            for (int j = 0; j < 64; j++) nz |= (er[2 * (base + j) + 1] != 0u);
            isl = nz ? 0 : 1;
        }
        lh[tid] = 0;
        __syncthreads();
        const int is64 = isl;
#pragma unroll 4
        for (int j = 0; j < CHUNK / 256; j++) {
            int e = base + j * 256 + tid;
            if (e < N_EDGES) {
                int sN, d;
                if (is64) { sN = (int)e64[e]; d = (int)e64[N_EDGES + e]; }
                else      { sN = e32[e];      d = e32[N_EDGES + e]; }
                int bb = d >> 8;
                int pos = atomicAdd(&lh[bb], 1);
                if (pos < SUBCAP) {   // 6.7-sigma guard
                    uint2 pr; pr.x = (unsigned)sN; pr.y = (unsigned)d;
                    ebuck2[((size_t)bb * NCHUNK + c) * SUBCAP + pos] = pr;
                }
            }
        }
        __syncthreads();
        int v = lh[tid]; if (v > SUBCAP) v = SUBCAP;
        cnt[c * 256 + tid] = v;
        return;
    }
    // ---- weight swizzle ----
    int t = b * 256 + tid;
    const float* W; int base, N;
    if (t < 8192)       { W = We; base = 0;     N = 64;  }
    else if (t < 16384) { W = Wd; base = 8192;  N = 128; }
    else if (t < 32768) { W = Wo; base = 16384; N = 128; }
    else                { W = Wg; base = SWZ_G; N = 128; }
    int loc = t - base;
    int nnt = N >> 4;
    int frag = loc >> 9, r = loc & 511, lane = r >> 3, j = r & 7;
    int kc = frag / nnt, nt = frag - kc * nnt;
    int k = kc * 32 + ((lane >> 4) << 3) + j;
    int n = nt * 16 + (lane & 15);
    swz[t] = (_Float16)W[k * N + n];
}

// ---------------- L2: bfill' blocks [0,196) ∥ gat_lin blocks [196,978) ---
__global__ __launch_bounds__(256) void k_lin_bfill(
        const float* __restrict__ x, const _Float16* __restrict__ swz,
        const float* __restrict__ att_s, const float* __restrict__ att_d,
        unsigned* __restrict__ h_bf, float* __restrict__ a_src,
        float* __restrict__ a_dst,
        const uint2* __restrict__ ebuck2, const int* __restrict__ cnt,
        int2* __restrict__ nodeoff, int* __restrict__ csr_src) {
    __shared__ __align__(16) char smem[SMEM_BYTES];
    const int tid = threadIdx.x;

    if (blockIdx.x < NBUCK) {
        // ---- bfill' for bucket bkt ----
        uint2* dense = (uint2*)smem;                     // DCAP*8 = 40960
        int*   coff  = (int*)(smem + 40960);             // 392*4  = 1568
        int*   sc    = (int*)(smem + 42528);             // 1024
        int*   lh    = (int*)(smem + 43552);             // 1024
        int*   lexc  = (int*)(smem + 44576);             // 1024
        int*   lcur  = (int*)(smem + 45600);             // 1024
        const int bkt = blockIdx.x;
        const int lo = bkt * CAP;
        const int n0 = bkt << 8;

        // A: chunk-count scan (391 values, two 256-wide rounds)
        int v0 = cnt[tid * 256 + bkt];                   // chunks 0..255
        sc[tid] = v0;
        __syncthreads();
        for (int o = 1; o < 256; o <<= 1) {
            int u = (tid >= o) ? sc[tid - o] : 0;
            __syncthreads();
            sc[tid] += u;
            __syncthreads();
        }
        coff[tid] = sc[tid] - v0;
        int total0 = sc[255];
        __syncthreads();
        int c2 = tid + 256;
        int v1 = (c2 < NCHUNK) ? cnt[c2 * 256 + bkt] : 0;
        sc[tid] = v1;
        __syncthreads();
        for (int o = 1; o < 256; o <<= 1) {
            int u = (tid >= o) ? sc[tid - o] : 0;
            __syncthreads();
            sc[tid] += u;
            __syncthreads();
        }
        if (c2 < NCHUNK) coff[c2] = total0 + sc[tid] - v1;
        int cntb = total0 + sc[255];
        if (cntb > DCAP) cntb = DCAP;
        if (tid == 0) coff[NCHUNK] = cntb;
        __syncthreads();

        // B: compact to dense LDS (8 threads per chunk, 32 chunks in flight)
        {
            int cg = tid >> 3, j = tid & 7;
            for (int c = cg; c < NCHUNK; c += 32) {
                int off = coff[c];
                int n = coff[c + 1] - off;
                const uint2* src = &ebuck2[((size_t)bkt * NCHUNK + c) * SUBCAP];
                for (int e = j; e < n; e += 8)
                    if (off + e < DCAP) dense[off + e] = src[e];
            }
        }
        __syncthreads();

        // C: node histogram from LDS
        lh[tid] = 0;
        lcur[tid] = 0;
        __syncthreads();
        for (int i = tid; i < cntb; i += 256)
            atomicAdd(&lh[dense[i].y & 255], 1);
        __syncthreads();

        // D: padded (x8) exclusive scan -> nodeoff
        int v = lh[tid];
        int p = (v + 7) & ~7;
        lexc[tid] = p;
        __syncthreads();
        for (int o = 1; o < 256; o <<= 1) {
            int u = (tid >= o) ? lexc[tid - o] : 0;
            __syncthreads();
            lexc[tid] += u;
            __syncthreads();
        }
        {
            int s = lexc[tid] - p;   // exclusive padded start
            lexc[tid] = s;
            int node = n0 + tid;
            if (node < N_NODES) {
                int2 no;
                no.x = lo + s;
                int maxlen = CAP - s; if (maxlen < 0) maxlen = 0;
                no.y = p <= maxlen ? p : (maxlen & ~7);
                nodeoff[node] = no;
            }
        }
        __syncthreads();

        // E: scatter + F: sentinel pad
        for (int i = tid; i < cntb; i += 256) {
            uint2 pr = dense[i];
            int li = (int)(pr.y & 255);
            int pos = atomicAdd(&lcur[li], 1);
            int dst = lexc[li] + pos;
            if (dst < CAP) csr_src[lo + dst] = (int)pr.x;
        }
        {
            int base2 = lexc[tid];
            for (int j = v; j < p && base2 + j < CAP; j++)
                csr_src[lo + base2 + j] = -1;
        }
        return;
    }

    // ---- gat_lin body: h(bf16) = x @ W_gat via MFMA; att head dots ----
    _Float16* sx = (_Float16*)smem;                    // 64 x SXP f16
    float*    sh = (float*)(smem + 64 * SXP * 2);      // 64 x 132 f32
    const int m0 = (blockIdx.x - NBUCK) * 64;

#pragma unroll
    for (int i = 0; i < 8; i++) {
        int idx = tid + i * 256;        // 2048 float4 slots (64 x 32)
        int r = idx >> 5, c4 = idx & 31;
        int row = m0 + r; if (row >= N_NODES) row = N_NODES - 1;
        float4 v = ((const float4*)(x + (size_t)row * 128))[c4];
        half4v h;
        h[0] = (_Float16)v.x; h[1] = (_Float16)v.y;
        h[2] = (_Float16)v.z; h[3] = (_Float16)v.w;
        *(half4v*)&sx[r * SXP + c4 * 4] = h;
    }
    __syncthreads();

    const int wave = tid >> 6, lane = tid & 63;
    const int lm = lane & 15, lq = lane >> 4;
    const int wrow = wave * 16;

    {
        float4v acc[8];
#pragma unroll
        for (int nt = 0; nt < 8; nt++) acc[nt] = (float4v){0.f, 0.f, 0.f, 0.f};
#pragma unroll
        for (int kc = 0; kc < 4; kc++) {
            half8 a = *(const half8*)&sx[(wrow + lm) * SXP + kc * 32 + lq * 8];
#pragma unroll
            for (int nt = 0; nt < 8; nt++) {
                half8 b = *(const half8*)&swz[SWZ_G + (kc * 8 + nt) * 512 + lane * 8];
                acc[nt] = __builtin_amdgcn_mfma_f32_16x16x32_f16(a, b, acc[nt], 0, 0, 0);
            }
        }
        // C/D layout: col = nt*16 + lm, row = lq*4 + r
#pragma unroll
        for (int nt = 0; nt < 8; nt++)
#pragma unroll
            for (int r = 0; r < 4; r++)
                sh[(wrow + lq * 4 + r) * 132 + nt * 16 + lm] = acc[nt][r];
    }
    __syncthreads();

    // epilogue: pack bf16 h + attention dots (8 rows x 4 cols per thread)
    const int c0 = (tid & 31) * 4;
    const int r0 = (tid >> 5) * 8;
    float4 as4 = *(const float4*)&att_s[c0];
    float4 ad4 = *(const float4*)&att_d[c0];
    const int head = c0 >> 5;

#pragma unroll
    for (int r = 0; r < 8; r++) {
        int row = m0 + r0 + r;
        bool ok = row < N_NODES;
        float4 hv = *(const float4*)&sh[(r0 + r) * 132 + c0];
        if (ok) {
            uint2 p;
            p.x = f2bf2(hv.x, hv.y);
            p.y = f2bf2(hv.z, hv.w);
            *(uint2*)&h_bf[(size_t)row * 64 + (c0 >> 1)] = p;
        }
        float vs = hv.x * as4.x + hv.y * as4.y + hv.z * as4.z + hv.w * as4.w;
        float vd = hv.x * ad4.x + hv.y * ad4.y + hv.z * ad4.z + hv.w * ad4.w;
#pragma unroll
        for (int o = 4; o >= 1; o >>= 1) {
            vs += __shfl_down(vs, o, 8);
            vd += __shfl_down(vd, o, 8);
        }
        if (ok && (tid & 7) == 0) {
            a_src[row * 4 + head] = vs;
            a_dst[row * 4 + head] = vd;
        }
    }
}

// ---------------- K3: CSR gather — 4 edge-groups x 16 lanes x 8 ch -------
// Lane (eg=lane>>4, lc=lane&15): channels 8lc..8lc+7 (head hd=lc>>2, never
// crosses a head boundary), edges {base+2eg, base+2eg+1} per 8-edge iter.
// Per lane per iter: 1 int2 idx (wave-broadcast) + 2 uint4 h + 2 a loads,
// 2x softmax scalar chains. Reduce across groups: shfl_xor 16,32.
__global__ __launch_bounds__(256) void k_gather(const int2* __restrict__ nodeoff,
        const int* __restrict__ csr_src, const float* __restrict__ a_src,
        const float* __restrict__ a_dst, const unsigned* __restrict__ h_bf,
        const float* __restrict__ b_gat, _Float16* __restrict__ x1) {
    int d = blockIdx.x * 4 + (threadIdx.x >> 6);
    if (d >= N_NODES) return;
    const int lane = threadIdx.x & 63;
    const int eg = lane >> 4;            // edge-slot group 0..3
    const int lc = lane & 15;            // channel octet 8lc..8lc+7
    const int hd = lc >> 2;              // head of this octet
    const uint4* hb = (const uint4*)h_bf;   // 16 uint4 per node row
    int2 nd = nodeoff[d];
    const int lo = nd.x, hi = nd.x + nd.y;   // padded len (x8)

    const float adh = a_dst[(unsigned)(d * 4 + hd)];

    float den = 0.f;
    float c0 = 0.f, c1 = 0.f, c2 = 0.f, c3 = 0.f;
    float c4 = 0.f, c5 = 0.f, c6 = 0.f, c7 = 0.f;

    if (eg == 0) {   // self-loop on group 0
        float t = a_src[(unsigned)(d * 4 + hd)] + adh;
        t = t > 0.f ? t : 0.2f * t;
        float es = __expf(t);
        den = es;
        uint4 u = hb[(unsigned)d * 16 + lc];
        float2 p0 = bf2f2(u.x), p1 = bf2f2(u.y), p2 = bf2f2(u.z), p3 = bf2f2(u.w);
        c0 = p0.x * es; c1 = p0.y * es; c2 = p1.x * es; c3 = p1.y * es;
        c4 = p2.x * es; c5 = p2.y * es; c6 = p3.x * es; c7 = p3.y * es;
    }

    for (int base = lo; base < hi; base += 8) {
        int2 sv = *(const int2*)&csr_src[base + eg * 2];
        int sA = sv.x, sB = sv.y;
        unsigned gA = (unsigned)(sA < 0 ? d : sA);
        unsigned gB = (unsigned)(sB < 0 ? d : sB);
        uint4 uA = hb[gA * 16 + lc];
        uint4 uB = hb[gB * 16 + lc];
        float aA = a_src[gA * 4 + hd];
        float aB = a_src[gB * 4 + hd];

        float tA = aA + adh; tA = tA > 0.f ? tA : 0.2f * tA;
        float tB = aB + adh; tB = tB > 0.f ? tB : 0.2f * tB;
        float eA = sA < 0 ? 0.f : __expf(tA);
        float eB = sB < 0 ? 0.f : __expf(tB);
        den += eA + eB;

        float2 p0, p1, p2, p3;
        p0 = bf2f2(uA.x); p1 = bf2f2(uA.y); p2 = bf2f2(uA.z); p3 = bf2f2(uA.w);
        c0 = fmaf(p0.x, eA, c0); c1 = fmaf(p0.y, eA, c1);
        c2 = fmaf(p1.x, eA, c2); c3 = fmaf(p1.y, eA, c3);
        c4 = fmaf(p2.x, eA, c4); c5 = fmaf(p2.y, eA, c5);
        c6 = fmaf(p3.x, eA, c6); c7 = fmaf(p3.y, eA, c7);
        p0 = bf2f2(uB.x); p1 = bf2f2(uB.y); p2 = bf2f2(uB.z); p3 = bf2f2(uB.w);
        c0 = fmaf(p0.x, eB, c0); c1 = fmaf(p0.y, eB, c1);
        c2 = fmaf(p1.x, eB, c2); c3 = fmaf(p1.y, eB, c3);
        c4 = fmaf(p2.x, eB, c4); c5 = fmaf(p2.y, eB, c5);
        c6 = fmaf(p3.x, eB, c6); c7 = fmaf(p3.y, eB, c7);
    }

    // reduce across the 4 edge-groups (lanes with same lc)
    den += __shfl_xor(den, 16);
    c0 += __shfl_xor(c0, 16); c1 += __shfl_xor(c1, 16);
    c2 += __shfl_xor(c2, 16); c3 += __shfl_xor(c3, 16);
    c4 += __shfl_xor(c4, 16); c5 += __shfl_xor(c5, 16);
    c6 += __shfl_xor(c6, 16); c7 += __shfl_xor(c7, 16);
    den += __shfl_xor(den, 32);
    c0 += __shfl_xor(c0, 32); c1 += __shfl_xor(c1, 32);
    c2 += __shfl_xor(c2, 32); c3 += __shfl_xor(c3, 32);
    c4 += __shfl_xor(c4, 32); c5 += __shfl_xor(c5, 32);
    c6 += __shfl_xor(c6, 32); c7 += __shfl_xor(c7, 32);

    if (lane < 16) {
        float inv = 1.f / (den + 1e-16f);
        float4 bg0 = ((const float4*)b_gat)[lc * 2];
        float4 bg1 = ((const float4*)b_gat)[lc * 2 + 1];
        half8 hv;
        hv[0] = (_Float16)elu_f(fmaf(c0, inv, bg0.x));
        hv[1] = (_Float16)elu_f(fmaf(c1, inv, bg0.y));
        hv[2] = (_Float16)elu_f(fmaf(c2, inv, bg0.z));
        hv[3] = (_Float16)elu_f(fmaf(c3, inv, bg0.w));
        hv[4] = (_Float16)elu_f(fmaf(c4, inv, bg1.x));
        hv[5] = (_Float16)elu_f(fmaf(c5, inv, bg1.y));
        hv[6] = (_Float16)elu_f(fmaf(c6, inv, bg1.z));
        hv[7] = (_Float16)elu_f(fmaf(c7, inv, bg1.w));
        *(half8*)&x1[(size_t)d * 128 + lc * 8] = hv;
    }
}

// ---------------- K4: fused MLP via MFMA f16 (f16 input, padded LDS) -----
__global__ __launch_bounds__(256) void k_mlp(const _Float16* __restrict__ x1,
        const _Float16* __restrict__ swz, const float* __restrict__ b_enc,
        const float* __restrict__ b_dec, const float* __restrict__ b_out,
        float* __restrict__ out) {
    __shared__ _Float16 sx[64 * SXP];          // 17 KB
    __shared__ _Float16 se[4 * 16 * SEP];      // 9 KB
    const int tid = threadIdx.x;
    const int m0 = blockIdx.x * 64;

    // stage X1 (already elu(agg+b_gat), f16) -> padded LDS, pure copies
#pragma unroll
    for (int i = 0; i < 4; i++) {
        int idx = tid + i * 256;        // 1024 uint4 slots (64 rows x 16)
        int r = idx >> 4, c = idx & 15;
        int row = m0 + r; if (row >= N_NODES) row = N_NODES - 1;
        uint4 v = ((const uint4*)(x1 + (size_t)row * 128))[c];
        *(uint4*)&sx[r * SXP + c * 8] = v;
    }
    __syncthreads();

    const int wave = tid >> 6, lane = tid & 63;
    const int lm = lane & 15, lq = lane >> 4;
    const int wrow = wave * 16;
    _Float16* eslab = &se[wave * 16 * SEP];

    // L1: E = X1 @ W_enc + b_enc
    {
        float4v acc[4];
#pragma unroll
        for (int nt = 0; nt < 4; nt++) acc[nt] = (float4v){0.f, 0.f, 0.f, 0.f};
#pragma unroll
        for (int kc = 0; kc < 4; kc++) {
            half8 a = *(const half8*)&sx[(wrow + lm) * SXP + kc * 32 + lq * 8];
#pragma unroll
            for (int nt = 0; nt < 4; nt++) {
                half8 b = *(const half8*)&swz[(kc * 4 + nt) * 512 + lane * 8];
                acc[nt] = __builtin_amdgcn_mfma_f32_16x16x32_f16(a, b, acc[nt], 0, 0, 0);
            }
        }
#pragma unroll
        for (int nt = 0; nt < 4; nt++) {
            float be = b_enc[nt * 16 + lm];
#pragma unroll
            for (int r = 0; r < 4; r++)
                eslab[(lq * 4 + r) * SEP + nt * 16 + lm] = (_Float16)(acc[nt][r] + be);
        }
    }

    // L2: X2 = elu(E @ W_dec + b_dec) -> sx slab
    {
        float4v acc[8];
#pragma unroll
        for (int nt = 0; nt < 8; nt++) acc[nt] = (float4v){0.f, 0.f, 0.f, 0.f};
#pragma unroll
        for (int kc = 0; kc < 2; kc++) {
            half8 a = *(const half8*)&eslab[lm * SEP + kc * 32 + lq * 8];
#pragma unroll
            for (int nt = 0; nt < 8; nt++) {
                half8 b = *(const half8*)&swz[8192 + (kc * 8 + nt) * 512 + lane * 8];
                acc[nt] = __builtin_amdgcn_mfma_f32_16x16x32_f16(a, b, acc[nt], 0, 0, 0);
            }
        }
#pragma unroll
        for (int nt = 0; nt < 8; nt++) {
            float bd = b_dec[nt * 16 + lm];
#pragma unroll
            for (int r = 0; r < 4; r++)
                sx[(wrow + lq * 4 + r) * SXP + nt * 16 + lm] =
                    (_Float16)elu_f(acc[nt][r] + bd);
        }
    }

    // L3: OUT = X2 @ W_out + b_out
    {
        float4v acc[8];
#pragma unroll
        for (int nt = 0; nt < 8; nt++) acc[nt] = (float4v){0.f, 0.f, 0.f, 0.f};
#pragma unroll
        for (int kc = 0; kc < 4; kc++) {
            half8 a = *(const half8*)&sx[(wrow + lm) * SXP + kc * 32 + lq * 8];
#pragma unroll
            for (int nt = 0; nt < 8; nt++) {
                half8 b = *(const half8*)&swz[16384 + (kc * 8 + nt) * 512 + lane * 8];
                acc[nt] = __builtin_amdgcn_mfma_f32_16x16x32_f16(a, b, acc[nt], 0, 0, 0);
            }
        }
#pragma unroll
        for (int nt = 0; nt < 8; nt++) {
            float bo = b_out[nt * 16 + lm];
#pragma unroll
            for (int r = 0; r < 4; r++) {
                int row = m0 + wrow + lq * 4 + r;
                if (row < N_NODES)
                    out[(size_t)row * 128 + nt * 16 + lm] = acc[nt][r] + bo;
            }
        }
    }
}

extern "C" void kernel_launch(void* const* d_in, const int* in_sizes, int n_in,
                              void* d_out, int out_size, void* d_ws, size_t ws_size,
                              hipStream_t stream) {
    const float* x       = (const float*)d_in[0];
    const void*  e_raw   = d_in[1];
    const float* W_gat   = (const float*)d_in[2];
    const float* b_gat   = (const float*)d_in[3];
    const float* att_src = (const float*)d_in[4];
    const float* att_dst = (const float*)d_in[5];
    const float* W_enc   = (const float*)d_in[6];
    const float* b_enc   = (const float*)d_in[7];
    const float* W_dec   = (const float*)d_in[8];
    const float* b_dec   = (const float*)d_in[9];
    const float* W_out   = (const float*)d_in[10];
    const float* b_out   = (const float*)d_in[11];
    float* out = (float*)d_out;

    float* ws      = (float*)d_ws;
    unsigned* h_bf = (unsigned*)ws;            // 3,200,000 u (50000 x 64)
    float* a_src   = ws + 6400000;             // 200,000 f
    float* a_dst   = a_src + 200000;           // 200,000 f
    float* agg     = a_dst + 200000;           // 6.4M-float region, reused:
    uint2* ebuck2  = (uint2*)agg;              //   196*391*32*8B = 19.6 MB
    _Float16* x1   = (_Float16*)agg;           //   12.8 MB (after bfill' done)
    int*   csr_src = (int*)(agg + 6400000);    // 196*8192 = 1,605,632 i
    int*   cnt     = csr_src + NBUCK * CAP;    // 391*256 = 100,096 i
    int2*  nodeoff = (int2*)(cnt + NCHUNK * 256);     // 50,000 int2
    _Float16* swz  = (_Float16*)(((uintptr_t)(nodeoff + 50000) + 15) & ~(uintptr_t)15);

    k_pre_bucket<<<SWZ_BLOCKS + NCHUNK, 256, 0, stream>>>(
        e_raw, W_enc, W_dec, W_out, W_gat, swz, ebuck2, cnt);

    k_lin_bfill<<<NBUCK + GBLK, 256, 0, stream>>>(
        x, swz, att_src, att_dst, h_bf, a_src, a_dst,
        ebuck2, cnt, nodeoff, csr_src);

    k_gather<<<(N_NODES + 3) / 4, 256, 0, stream>>>(
        nodeoff, csr_src, a_src, a_dst, h_bf, b_gat, x1);

    k_mlp<<<GBLK, 256, 0, stream>>>(x1, swz, b_enc, b_dec, b_out, out);
}